// Round 3
// baseline (486.455 us; speedup 1.0000x reference)
//
#include <hip/hip_runtime.h>
#include <math.h>

// PhaseRefinement fused kernel, v3: barrier-free main loop.
// Each block = 8 waves over 8 rows; wave wv computes the full-row dots for
// its 4 planes (planes wv*4..wv*4+3) for ALL 8 rows, reading x and W
// directly from global. Within a block the 8 waves read the same x rows
// ~simultaneously -> 1 HBM fetch + 7 L2 hits. No __syncthreads until the
// tail gather, so loads free-run (TLP across uncoupled waves hides HBM
// latency; R2's per-chunk barrier drained vmcnt(0) and exposed ~600cyc/chunk).
//
// out = x + LN(c*x)*gamma + beta; LN(c*x) collapses to
//   normed = gamma*(alpha*x - alpha*mu) + beta,
//   alpha = c*rsqrt(c^2*var + 1e-5), mu/var = plain row stats of x.

constexpr int Dh     = 4096;
constexpr int Ph     = 16;
constexpr int NPL    = 32;          // 2*P dots per row
constexpr int CHUNK  = 256;         // 64 lanes * 4 floats
constexpr int NCHUNK = Dh / CHUNK;  // 16
constexpr int RPB    = 8;           // rows per block
constexpr int NW     = 8;           // waves per block
constexpr int PPW    = NPL / NW;    // 4 planes per wave
constexpr int BLOCK  = 64 * NW;     // 512

__global__ __launch_bounds__(BLOCK, 4)
void phase_fused(const float* __restrict__ x,
                 const float* __restrict__ Wr,
                 const float* __restrict__ br,
                 const float* __restrict__ Wo,
                 const float* __restrict__ bo,
                 const float* __restrict__ gamma,
                 const float* __restrict__ beta,
                 float* __restrict__ out)
{
    __shared__ float dots_lds[RPB][NPL];
    __shared__ float stats_lds[RPB][2];
    __shared__ float scale_lds[RPB][2];

    const int t    = threadIdx.x;
    const int wv   = t >> 6;
    const int lane = t & 63;
    const size_t rowbase = (size_t)blockIdx.x * RPB;

    // Per-lane base pointers (lane offset folded in).
    const float* xrow[RPB];
#pragma unroll
    for (int r = 0; r < RPB; ++r)
        xrow[r] = x + (rowbase + r) * (size_t)Dh + lane * 4;

    const float* wrow[PPW];
#pragma unroll
    for (int p = 0; p < PPW; ++p) {
        const int q = wv * PPW + p;
        wrow[p] = ((q < Ph) ? (Wr + (size_t)q * Dh) : (Wo + (size_t)(q - Ph) * Dh))
                  + lane * 4;
    }

    float acc[RPB][PPW];
#pragma unroll
    for (int r = 0; r < RPB; ++r)
#pragma unroll
        for (int p = 0; p < PPW; ++p) acc[r][p] = 0.f;
    float sx = 0.f, sxx = 0.f;

    for (int c = 0; c < NCHUNK; ++c) {
        const int off = c * CHUNK;
        // Issue all 12 loads up front; no barriers anywhere -> they pipeline.
        float4 x4[RPB];
#pragma unroll
        for (int r = 0; r < RPB; ++r)
            x4[r] = *(const float4*)(xrow[r] + off);
        float4 w4[PPW];
#pragma unroll
        for (int p = 0; p < PPW; ++p)
            w4[p] = *(const float4*)(wrow[p] + off);

#pragma unroll
        for (int r = 0; r < RPB; ++r) {
            if (r == wv) {  // wave-uniform scalar branch; static indices
                sx  += x4[r].x + x4[r].y + x4[r].z + x4[r].w;
                sxx += x4[r].x*x4[r].x + x4[r].y*x4[r].y
                     + x4[r].z*x4[r].z + x4[r].w*x4[r].w;
            }
#pragma unroll
            for (int p = 0; p < PPW; ++p)
                acc[r][p] += x4[r].x*w4[p].x + x4[r].y*w4[p].y
                           + x4[r].z*w4[p].z + x4[r].w*w4[p].w;
        }
    }

    // Butterfly-reduce accumulators across the 64 lanes.
#pragma unroll
    for (int r = 0; r < RPB; ++r)
#pragma unroll
        for (int p = 0; p < PPW; ++p) {
            float v = acc[r][p];
#pragma unroll
            for (int m = 1; m < 64; m <<= 1) v += __shfl_xor(v, m, 64);
            if (lane == 0) dots_lds[r][wv * PPW + p] = v;
        }
#pragma unroll
    for (int m = 1; m < 64; m <<= 1) {
        sx  += __shfl_xor(sx, m, 64);
        sxx += __shfl_xor(sxx, m, 64);
    }
    if (lane == 0) { stats_lds[wv][0] = sx; stats_lds[wv][1] = sxx; }
    __syncthreads();

    // Per-row scalar phase (8 threads, one per row).
    if (t < RPB) {
        const int r = t;
        float s = 0.f;
#pragma unroll
        for (int p = 0; p < Ph; ++p) {
            float rp = tanhf(dots_lds[r][p]      + br[p]);
            float op = tanhf(dots_lds[r][Ph + p] + bo[p]);
            s += cosf((rp - op) * 3.14159265358979323846f);
        }
        float gain = log1pf(expf(s * (1.f / Ph) + 0.5f));   // softplus(resonance+0.5)
        float cm   = s * gain * (1.f / Ph);                  // per-row scalar c
        float mu   = stats_lds[r][0] * (1.f / Dh);
        float var  = stats_lds[r][1] * (1.f / Dh) - mu * mu;
        var = fmaxf(var, 0.f);
        float rstd  = rsqrtf(cm * cm * var + 1e-5f);
        float alpha = cm * rstd;
        scale_lds[r][0] = alpha;
        scale_lds[r][1] = alpha * mu;
    }
    __syncthreads();

    // Phase B: wave wv writes row wv; x re-read is L2-hot (R1/R2 FETCH_SIZE
    // confirmed ~x-once total).
    {
        const float alpha = scale_lds[wv][0];
        const float am    = scale_lds[wv][1];
        const float* xr = x   + (rowbase + wv) * (size_t)Dh;
        float* orow     = out + (rowbase + wv) * (size_t)Dh;
#pragma unroll
        for (int i = 0; i < Dh / (64 * 4); ++i) {   // 16 iterations
            const int col = i * 256 + lane * 4;
            float4 xv = *(const float4*)(xr + col);
            float4 g  = *(const float4*)(gamma + col);
            float4 bb = *(const float4*)(beta + col);
            float4 o;
            o.x = xv.x + g.x * (alpha * xv.x - am) + bb.x;
            o.y = xv.y + g.y * (alpha * xv.y - am) + bb.y;
            o.z = xv.z + g.z * (alpha * xv.z - am) + bb.z;
            o.w = xv.w + g.w * (alpha * xv.w - am) + bb.w;
            *(float4*)(orow + col) = o;
        }
    }
}

extern "C" void kernel_launch(void* const* d_in, const int* in_sizes, int n_in,
                              void* d_out, int out_size, void* d_ws, size_t ws_size,
                              hipStream_t stream)
{
    const float* x     = (const float*)d_in[0];
    const float* Wr    = (const float*)d_in[1];
    const float* br    = (const float*)d_in[2];
    const float* Wo    = (const float*)d_in[3];
    const float* bo    = (const float*)d_in[4];
    const float* gamma = (const float*)d_in[5];
    const float* beta  = (const float*)d_in[6];
    float* out = (float*)d_out;

    const int B = in_sizes[0] / Dh;       // 32768
    dim3 grid(B / RPB);                   // 4096 blocks
    phase_fused<<<grid, BLOCK, 0, stream>>>(x, Wr, br, Wo, bo, gamma, beta, out);
}